// Round 1
// baseline (77145.630 us; speedup 1.0000x reference)
//
#include <hip/hip_runtime.h>
#include <math.h>

// ESN reservoir: B=1, T=2048, I=8, R=4096, O=8.
// h_t = tanh(Win x_t + W h_{t-1}); y_t = Wout h_t + b.
// Strategy: persistent cooperative kernel, 256 WGs (1/CU), sparse W (10% nnz)
// compacted into LDS once; per-step all-to-all h exchange via monotonic
// history buffer + per-WG progress flags (agent-scope release/acquire).

#define T_STEPS 2048
#define R_DIM   4096
#define I_DIM   8
#define O_DIM   8
#define NWG     256
#define ROWS_PER_WG (R_DIM / NWG)   // 16
#define POOL_CAP 8192               // >= 21 sigma above mean nnz (6554) for 16 rows
#define BLOCK    256

// Static device buffers: no dependence on ws_size, no hipMalloc.
__device__ float        g_hist[(size_t)T_STEPS * R_DIM];  // 32 MB
__device__ unsigned int g_prog[NWG];

__global__ void esn_init_kernel() {
    if (threadIdx.x < NWG) g_prog[threadIdx.x] = 0u;
}

__launch_bounds__(BLOCK, 1)
__global__ void esn_recur_kernel(const float* __restrict__ x,
                                 const float* __restrict__ Win,
                                 const float* __restrict__ W) {
    __shared__ float s_val[POOL_CAP];                 // 32 KB
    __shared__ int   s_idx[POOL_CAP];                 // 32 KB
    __shared__ float s_h[R_DIM];                      // 16 KB
    __shared__ int   s_start[ROWS_PER_WG + 1];
    __shared__ int   s_cnt[ROWS_PER_WG];
    __shared__ float s_win[ROWS_PER_WG][I_DIM];       // 512 B

    const int wg   = blockIdx.x;
    const int tid  = threadIdx.x;
    const int lane = tid & 63;
    const int wave = tid >> 6;
    const int row0 = wg * ROWS_PER_WG;

    // ---------- one-time setup: compact this WG's 16 rows of W into LDS ----------
    // pass 1: count nnz per row (wave v handles rows v, v+4, v+8, v+12)
    for (int rr = wave; rr < ROWS_PER_WG; rr += 4) {
        const float* wrow = W + (size_t)(row0 + rr) * R_DIM;
        int cnt = 0;
        for (int base = 0; base < R_DIM; base += 64) {
            float v = wrow[base + lane];
            unsigned long long m = __ballot(v != 0.0f);
            cnt += __popcll(m);
        }
        if (lane == 0) s_cnt[rr] = cnt;
    }
    __syncthreads();
    if (tid == 0) {
        int acc = 0;
        for (int rr = 0; rr < ROWS_PER_WG; ++rr) {
            s_start[rr] = (acc < POOL_CAP) ? acc : POOL_CAP;
            acc += s_cnt[rr];
        }
        s_start[ROWS_PER_WG] = (acc < POOL_CAP) ? acc : POOL_CAP;
    }
    __syncthreads();
    // pass 2: fill (ballot-prefix compaction)
    for (int rr = wave; rr < ROWS_PER_WG; rr += 4) {
        const float* wrow = W + (size_t)(row0 + rr) * R_DIM;
        int off = s_start[rr];
        for (int base = 0; base < R_DIM; base += 64) {
            float v = wrow[base + lane];
            unsigned long long m = __ballot(v != 0.0f);
            int pre = __popcll(m & ((1ull << lane) - 1ull));
            if (v != 0.0f) {
                int pos = off + pre;
                if (pos < POOL_CAP) { s_val[pos] = v; s_idx[pos] = base + lane; }
            }
            off += __popcll(m);
        }
    }
    // Win rows for this WG
    if (tid < ROWS_PER_WG * I_DIM) {
        int rr = tid / I_DIM, c = tid % I_DIM;
        s_win[rr][c] = Win[(size_t)(row0 + rr) * I_DIM + c];
    }
    __syncthreads();

    const int row16 = tid >> 4;          // 0..15: which of my 16 rows
    const int sub   = tid & 15;          // 16 threads per row
    const int start = s_start[row16];
    const int cnt   = s_start[row16 + 1] - start;

    // ---------- time loop ----------
    for (int t = 0; t < T_STEPS; ++t) {
        if (t > 0) {
            // wait for all 256 producers to have published h_{t-1}
            while (__hip_atomic_load(&g_prog[tid], __ATOMIC_ACQUIRE,
                                     __HIP_MEMORY_SCOPE_AGENT) < (unsigned)t) {
                __builtin_amdgcn_s_sleep(1);
            }
            __syncthreads();
            // broadcast-read h_{t-1} into LDS (coalesced float4)
            const float4* src = (const float4*)(g_hist + (size_t)(t - 1) * R_DIM);
            float4* dst = (float4*)s_h;
            #pragma unroll
            for (int i = 0; i < (R_DIM / 4) / BLOCK; ++i)
                dst[tid + i * BLOCK] = src[tid + i * BLOCK];
            __syncthreads();
        }

        // sparse row-dot: this thread does every 16th nnz of its row
        float acc = 0.0f;
        if (t > 0) {
            for (int e = start + sub; e < start + cnt; e += 16)
                acc += s_val[e] * s_h[s_idx[e]];
        }
        // reduce across the 16-lane group
        acc += __shfl_xor(acc, 8, 16);
        acc += __shfl_xor(acc, 4, 16);
        acc += __shfl_xor(acc, 2, 16);
        acc += __shfl_xor(acc, 1, 16);

        if (sub == 0) {
            const float* xt = x + (size_t)t * I_DIM;
            float a = acc;
            #pragma unroll
            for (int c = 0; c < I_DIM; ++c) a += s_win[row16][c] * xt[c];
            float h = tanhf(a);
            g_hist[(size_t)t * R_DIM + row0 + row16] = h;
        }
        // publish: make h stores agent-visible, then bump progress
        __threadfence();
        __syncthreads();
        if (tid == 0)
            __hip_atomic_store(&g_prog[wg], (unsigned)(t + 1), __ATOMIC_RELEASE,
                               __HIP_MEMORY_SCOPE_AGENT);
    }
}

// y_t = Wout h_t + b, one wave per timestep
__global__ void esn_out_kernel(const float* __restrict__ Wout_w,
                               const float* __restrict__ Wout_b,
                               float* __restrict__ out) {
    const int t = blockIdx.x;
    const int lane = threadIdx.x;  // 64 threads
    const float* h = g_hist + (size_t)t * R_DIM;
    float acc[O_DIM];
    #pragma unroll
    for (int o = 0; o < O_DIM; ++o) acc[o] = 0.0f;
    for (int i = lane; i < R_DIM; i += 64) {
        float hv = h[i];
        #pragma unroll
        for (int o = 0; o < O_DIM; ++o)
            acc[o] += hv * Wout_w[(size_t)o * R_DIM + i];
    }
    #pragma unroll
    for (int o = 0; o < O_DIM; ++o) {
        float a = acc[o];
        a += __shfl_xor(a, 32);
        a += __shfl_xor(a, 16);
        a += __shfl_xor(a, 8);
        a += __shfl_xor(a, 4);
        a += __shfl_xor(a, 2);
        a += __shfl_xor(a, 1);
        if (lane == 0) out[(size_t)t * O_DIM + o] = a + Wout_b[o];
    }
}

extern "C" void kernel_launch(void* const* d_in, const int* in_sizes, int n_in,
                              void* d_out, int out_size, void* d_ws, size_t ws_size,
                              hipStream_t stream) {
    const float* x    = (const float*)d_in[0];   // [1,2048,8]
    const float* Win  = (const float*)d_in[1];   // [4096,8]
    const float* W    = (const float*)d_in[2];   // [4096,4096]
    const float* Ww   = (const float*)d_in[3];   // [8,4096]
    const float* Wb   = (const float*)d_in[4];   // [8]
    float* out = (float*)d_out;                  // [1,2048,8]

    hipLaunchKernelGGL(esn_init_kernel, dim3(1), dim3(256), 0, stream);

    void* args[] = { (void*)&x, (void*)&Win, (void*)&W };
    hipLaunchCooperativeKernel((void*)esn_recur_kernel, dim3(NWG), dim3(BLOCK),
                               args, 0, stream);

    hipLaunchKernelGGL(esn_out_kernel, dim3(T_STEPS), dim3(64), 0, stream,
                       Ww, Wb, out);
}

// Round 4
// 14912.155 us; speedup vs baseline: 5.1733x; 5.1733x over previous
//
#include <hip/hip_runtime.h>
#include <math.h>

// ESN reservoir: B=1, T=2048, I=8, R=4096, O=8.
// h_t = tanh(Win x_t + W h_{t-1}); y_t = Wout h_t + b.
//
// R4 = R1's exact numerics (BLOCK=256, 16 threads/row, identical reduction
// order -> passed at absmax 0.0078, 8x margin) + fast sync:
//  - producer h & flag stores: relaxed SYSTEM scope (write-through, no wbL2)
//  - flag polls: relaxed SYSTEM loads (L2-bypass; also required since remote
//    write-through stores never invalidate this XCD's L2 copy)
//  - consumer h reads: global_load_dwordx4 sc0 sc1 (L2-bypass, L3-served;
//    immune to stale L2 lines on first launch AND across graph replays)
//  - release ordering: s_waitcnt vmcnt(0) + __syncthreads, no cache ops.

#define T_STEPS 2048
#define R_DIM   4096
#define I_DIM   8
#define O_DIM   8
#define NWG     256
#define ROWS_PER_WG (R_DIM / NWG)   // 16
#define POOL_CAP 8192               // mean nnz/WG = 6554, ~21 sigma headroom
#define BLOCK    256

typedef float v4f __attribute__((ext_vector_type(4)));

__device__ float        g_hist[(size_t)T_STEPS * R_DIM];  // 32 MB
__device__ unsigned int g_prog[NWG];

__global__ void esn_init_kernel() {
    if (threadIdx.x < NWG)
        __hip_atomic_store(&g_prog[threadIdx.x], 0u, __ATOMIC_RELAXED,
                           __HIP_MEMORY_SCOPE_SYSTEM);
}

__launch_bounds__(BLOCK, 1)
__global__ void esn_recur_kernel(const float* __restrict__ x,
                                 const float* __restrict__ Win,
                                 const float* __restrict__ W) {
    __shared__ float s_val[POOL_CAP];                 // 32 KB
    __shared__ int   s_idx[POOL_CAP];                 // 32 KB
    __shared__ float s_h[R_DIM];                      // 16 KB
    __shared__ int   s_start[ROWS_PER_WG + 1];
    __shared__ int   s_cnt[ROWS_PER_WG];
    __shared__ float s_win[ROWS_PER_WG][I_DIM];

    const int wg   = blockIdx.x;
    const int tid  = threadIdx.x;
    const int lane = tid & 63;
    const int wave = tid >> 6;
    const int row0 = wg * ROWS_PER_WG;

    // ---------- one-time setup: compact 16 rows of W into LDS (as R1) ----------
    for (int rr = wave; rr < ROWS_PER_WG; rr += 4) {
        const float* wrow = W + (size_t)(row0 + rr) * R_DIM;
        int cnt = 0;
        for (int base = 0; base < R_DIM; base += 64) {
            float v = wrow[base + lane];
            cnt += __popcll(__ballot(v != 0.0f));
        }
        if (lane == 0) s_cnt[rr] = cnt;
    }
    __syncthreads();
    if (tid == 0) {
        int acc = 0;
        for (int rr = 0; rr < ROWS_PER_WG; ++rr) {
            s_start[rr] = (acc < POOL_CAP) ? acc : POOL_CAP;
            acc += s_cnt[rr];
        }
        s_start[ROWS_PER_WG] = (acc < POOL_CAP) ? acc : POOL_CAP;
    }
    __syncthreads();
    for (int rr = wave; rr < ROWS_PER_WG; rr += 4) {
        const float* wrow = W + (size_t)(row0 + rr) * R_DIM;
        int off = s_start[rr];
        for (int base = 0; base < R_DIM; base += 64) {
            float v = wrow[base + lane];
            unsigned long long m = __ballot(v != 0.0f);
            int pre = __popcll(m & ((1ull << lane) - 1ull));
            if (v != 0.0f) {
                int pos = off + pre;
                if (pos < POOL_CAP) { s_val[pos] = v; s_idx[pos] = base + lane; }
            }
            off += __popcll(m);
        }
    }
    if (tid < ROWS_PER_WG * I_DIM) {
        int rr = tid / I_DIM, c = tid % I_DIM;
        s_win[rr][c] = Win[(size_t)(row0 + rr) * I_DIM + c];
    }
    __syncthreads();

    const int row16 = tid >> 4;          // 0..15: which of my 16 rows
    const int sub   = tid & 15;          // 16 threads per row (as R1)
    const int start = s_start[row16];
    const int cnt   = s_start[row16 + 1] - start;

    // ---------- time loop ----------
    for (int t = 0; t < T_STEPS; ++t) {
        if (t > 0) {
            // poll all 256 producer flags: relaxed SYSTEM loads (L2-bypass)
            while (__hip_atomic_load(&g_prog[tid], __ATOMIC_RELAXED,
                                     __HIP_MEMORY_SCOPE_SYSTEM) < (unsigned)t)
                __builtin_amdgcn_s_sleep(1);
            __syncthreads();
            // broadcast-read h_{t-1} into LDS: 16 KB via dwordx4 sc0 sc1
            // (L2-bypass -> always fresh from L3, no cache-maintenance ops)
            const v4f* src = (const v4f*)(g_hist + (size_t)(t - 1) * R_DIM);
            v4f r0, r1, r2, r3;
            const v4f* a0 = src + tid;
            const v4f* a1 = src + tid + 256;
            const v4f* a2 = src + tid + 512;
            const v4f* a3 = src + tid + 768;
            asm volatile(
                "global_load_dwordx4 %0, %4, off sc0 sc1\n\t"
                "global_load_dwordx4 %1, %5, off sc0 sc1\n\t"
                "global_load_dwordx4 %2, %6, off sc0 sc1\n\t"
                "global_load_dwordx4 %3, %7, off sc0 sc1\n\t"
                "s_waitcnt vmcnt(0)"
                : "=v"(r0), "=v"(r1), "=v"(r2), "=v"(r3)
                : "v"(a0), "v"(a1), "v"(a2), "v"(a3)
                : "memory");
            v4f* dst = (v4f*)s_h;
            dst[tid]       = r0;
            dst[tid + 256] = r1;
            dst[tid + 512] = r2;
            dst[tid + 768] = r3;
            __syncthreads();
        }

        // sparse row-dot: identical order to R1 (16-lane groups, stride 16)
        float acc = 0.0f;
        if (t > 0) {
            for (int e = start + sub; e < start + cnt; e += 16)
                acc += s_val[e] * s_h[s_idx[e]];
        }
        acc += __shfl_xor(acc, 8, 16);
        acc += __shfl_xor(acc, 4, 16);
        acc += __shfl_xor(acc, 2, 16);
        acc += __shfl_xor(acc, 1, 16);

        if (sub == 0) {
            const float* xt = x + (size_t)t * I_DIM;
            float a = acc;
            #pragma unroll
            for (int c = 0; c < I_DIM; ++c) a += s_win[row16][c] * xt[c];
            float h = tanhf(a);
            // write-through to coherence point (no dirty L2 line)
            __hip_atomic_store(&g_hist[(size_t)t * R_DIM + row0 + row16], h,
                               __ATOMIC_RELAXED, __HIP_MEMORY_SCOPE_SYSTEM);
        }
        // release: drain this wave's stores, join waves, bump flag
        asm volatile("s_waitcnt vmcnt(0)" ::: "memory");
        __syncthreads();
        if (tid == 0)
            __hip_atomic_store(&g_prog[wg], (unsigned)(t + 1), __ATOMIC_RELAXED,
                               __HIP_MEMORY_SCOPE_SYSTEM);
    }
}

// y_t = Wout h_t + b, one wave per timestep; h reads are SYSTEM-scope scalar
// loads (L2-bypass) so graph-replay L2 staleness can't bite; accumulation
// order identical to R1.
__global__ void esn_out_kernel(const float* __restrict__ Wout_w,
                               const float* __restrict__ Wout_b,
                               float* __restrict__ out) {
    const int t = blockIdx.x;
    const int lane = threadIdx.x;  // 64 threads
    const float* h = g_hist + (size_t)t * R_DIM;
    float acc[O_DIM];
    #pragma unroll
    for (int o = 0; o < O_DIM; ++o) acc[o] = 0.0f;
    for (int i = lane; i < R_DIM; i += 64) {
        float hv = __hip_atomic_load(&h[i], __ATOMIC_RELAXED,
                                     __HIP_MEMORY_SCOPE_SYSTEM);
        #pragma unroll
        for (int o = 0; o < O_DIM; ++o)
            acc[o] += hv * Wout_w[(size_t)o * R_DIM + i];
    }
    #pragma unroll
    for (int o = 0; o < O_DIM; ++o) {
        float a = acc[o];
        a += __shfl_xor(a, 32);
        a += __shfl_xor(a, 16);
        a += __shfl_xor(a, 8);
        a += __shfl_xor(a, 4);
        a += __shfl_xor(a, 2);
        a += __shfl_xor(a, 1);
        if (lane == 0) out[(size_t)t * O_DIM + o] = a + Wout_b[o];
    }
}

extern "C" void kernel_launch(void* const* d_in, const int* in_sizes, int n_in,
                              void* d_out, int out_size, void* d_ws, size_t ws_size,
                              hipStream_t stream) {
    const float* x    = (const float*)d_in[0];   // [1,2048,8]
    const float* Win  = (const float*)d_in[1];   // [4096,8]
    const float* W    = (const float*)d_in[2];   // [4096,4096]
    const float* Ww   = (const float*)d_in[3];   // [8,4096]
    const float* Wb   = (const float*)d_in[4];   // [8]
    float* out = (float*)d_out;                  // [1,2048,8]

    hipLaunchKernelGGL(esn_init_kernel, dim3(1), dim3(256), 0, stream);

    void* args[] = { (void*)&x, (void*)&Win, (void*)&W };
    hipLaunchCooperativeKernel((void*)esn_recur_kernel, dim3(NWG), dim3(BLOCK),
                               args, 0, stream);

    hipLaunchKernelGGL(esn_out_kernel, dim3(T_STEPS), dim3(64), 0, stream,
                       Ww, Wb, out);
}

// Round 5
// 12970.860 us; speedup vs baseline: 5.9476x; 1.1497x over previous
//
#include <hip/hip_runtime.h>
#include <math.h>

// ESN reservoir: B=1, T=2048, I=8, R=4096, O=8.
// h_t = tanh(Win x_t + W h_{t-1}); y_t = Wout h_t + b.
//
// R5: flagless sync. Each h element is published as an 8-byte packet
// (tag<<32 | float_bits) with a per-launch-unique tag (epoch from init
// kernel), stored relaxed SYSTEM scope (write-through). Consumers read
// h_{t-1} packets directly with 16 pipelined global_load_dwordx2 sc0 sc1
// (one asm block -> all 16 in flight) and retry only stale rows.
// No flag array (R4's 16 hot flag lines were the congestion point), no
// producer store-ack wait: critical path = store -> read (~1.5 L3 RTs).
// Compute & reduction order bit-identical to R4 (absmax 0.0078125, 8x margin).

#define T_STEPS 2048
#define R_DIM   4096
#define I_DIM   8
#define O_DIM   8
#define NWG     256
#define ROWS_PER_WG (R_DIM / NWG)   // 16
#define POOL_CAP 8192               // mean nnz/WG = 6554, ~21 sigma headroom
#define BLOCK    256
#define TAG_MUL  4096

__device__ unsigned long long g_pack[(size_t)T_STEPS * R_DIM];  // 64 MB
__device__ unsigned int      g_epoch;

__global__ void esn_init_kernel() {
    if (threadIdx.x == 0) {
        unsigned e = __hip_atomic_load(&g_epoch, __ATOMIC_RELAXED,
                                       __HIP_MEMORY_SCOPE_SYSTEM) + 1u;
        __hip_atomic_store(&g_epoch, e, __ATOMIC_RELAXED,
                           __HIP_MEMORY_SCOPE_SYSTEM);
    }
}

__launch_bounds__(BLOCK, 1)
__global__ void esn_recur_kernel(const float* __restrict__ x,
                                 const float* __restrict__ Win,
                                 const float* __restrict__ W) {
    __shared__ uint2 s_pool[POOL_CAP];                // 64 KB (val bits, idx)
    __shared__ float s_h[R_DIM];                      // 16 KB
    __shared__ int   s_start[ROWS_PER_WG + 1];
    __shared__ int   s_cnt[ROWS_PER_WG];
    __shared__ float s_win[ROWS_PER_WG][I_DIM];

    const int wg   = blockIdx.x;
    const int tid  = threadIdx.x;
    const int lane = tid & 63;
    const int wave = tid >> 6;
    const int row0 = wg * ROWS_PER_WG;

    const unsigned tag_base =
        __hip_atomic_load(&g_epoch, __ATOMIC_RELAXED,
                          __HIP_MEMORY_SCOPE_SYSTEM) * TAG_MUL;

    // ---------- one-time setup: compact 16 rows of W into LDS (order as R4) ----------
    for (int rr = wave; rr < ROWS_PER_WG; rr += 4) {
        const float* wrow = W + (size_t)(row0 + rr) * R_DIM;
        int cnt = 0;
        for (int base = 0; base < R_DIM; base += 64) {
            float v = wrow[base + lane];
            cnt += __popcll(__ballot(v != 0.0f));
        }
        if (lane == 0) s_cnt[rr] = cnt;
    }
    __syncthreads();
    if (tid == 0) {
        int acc = 0;
        for (int rr = 0; rr < ROWS_PER_WG; ++rr) {
            s_start[rr] = (acc < POOL_CAP) ? acc : POOL_CAP;
            acc += s_cnt[rr];
        }
        s_start[ROWS_PER_WG] = (acc < POOL_CAP) ? acc : POOL_CAP;
    }
    __syncthreads();
    for (int rr = wave; rr < ROWS_PER_WG; rr += 4) {
        const float* wrow = W + (size_t)(row0 + rr) * R_DIM;
        int off = s_start[rr];
        for (int base = 0; base < R_DIM; base += 64) {
            float v = wrow[base + lane];
            unsigned long long m = __ballot(v != 0.0f);
            int pre = __popcll(m & ((1ull << lane) - 1ull));
            if (v != 0.0f) {
                int pos = off + pre;
                if (pos < POOL_CAP) {
                    s_pool[pos].x = __float_as_uint(v);
                    s_pool[pos].y = base + lane;
                }
            }
            off += __popcll(m);
        }
    }
    if (tid < ROWS_PER_WG * I_DIM) {
        int rr = tid / I_DIM, c = tid % I_DIM;
        s_win[rr][c] = Win[(size_t)(row0 + rr) * I_DIM + c];
    }
    __syncthreads();

    const int row16 = tid >> 4;          // 0..15: which of my 16 rows
    const int sub   = tid & 15;          // 16 threads per row (as R4)
    const int start = s_start[row16];
    const int cnt   = s_start[row16 + 1] - start;

    // ---------- time loop ----------
    for (int t = 0; t < T_STEPS; ++t) {
        if (t > 0) {
            const unsigned exp_tag = tag_base + (unsigned)t;  // producer wrote t-1 with tag_base+t
            __syncthreads();   // previous step's s_h readers done
            const unsigned long long* base =
                g_pack + (size_t)(t - 1) * R_DIM + tid;
            unsigned long long u0,u1,u2,u3,u4,u5,u6,u7,u8,u9,u10,u11,u12,u13,u14,u15;
            const unsigned long long* a0 = base;
            const unsigned long long* a1 = base + 512;
            const unsigned long long* a2 = base + 1024;
            const unsigned long long* a3 = base + 1536;
            const unsigned long long* a4 = base + 2048;
            const unsigned long long* a5 = base + 2560;
            const unsigned long long* a6 = base + 3072;
            const unsigned long long* a7 = base + 3584;
            // 16 loads in flight, then one wait: ~1 L3 round trip total
            asm volatile(
                "global_load_dwordx2 %0,  %16, off sc0 sc1\n\t"
                "global_load_dwordx2 %1,  %16, off offset:2048 sc0 sc1\n\t"
                "global_load_dwordx2 %2,  %17, off sc0 sc1\n\t"
                "global_load_dwordx2 %3,  %17, off offset:2048 sc0 sc1\n\t"
                "global_load_dwordx2 %4,  %18, off sc0 sc1\n\t"
                "global_load_dwordx2 %5,  %18, off offset:2048 sc0 sc1\n\t"
                "global_load_dwordx2 %6,  %19, off sc0 sc1\n\t"
                "global_load_dwordx2 %7,  %19, off offset:2048 sc0 sc1\n\t"
                "global_load_dwordx2 %8,  %20, off sc0 sc1\n\t"
                "global_load_dwordx2 %9,  %20, off offset:2048 sc0 sc1\n\t"
                "global_load_dwordx2 %10, %21, off sc0 sc1\n\t"
                "global_load_dwordx2 %11, %21, off offset:2048 sc0 sc1\n\t"
                "global_load_dwordx2 %12, %22, off sc0 sc1\n\t"
                "global_load_dwordx2 %13, %22, off offset:2048 sc0 sc1\n\t"
                "global_load_dwordx2 %14, %23, off sc0 sc1\n\t"
                "global_load_dwordx2 %15, %23, off offset:2048 sc0 sc1\n\t"
                "s_waitcnt vmcnt(0)"
                : "=v"(u0), "=v"(u1), "=v"(u2), "=v"(u3),
                  "=v"(u4), "=v"(u5), "=v"(u6), "=v"(u7),
                  "=v"(u8), "=v"(u9), "=v"(u10), "=v"(u11),
                  "=v"(u12), "=v"(u13), "=v"(u14), "=v"(u15)
                : "v"(a0), "v"(a1), "v"(a2), "v"(a3),
                  "v"(a4), "v"(a5), "v"(a6), "v"(a7)
                : "memory");
            // retry only stale rows, then deposit into LDS
            #define FINISH_ROW(uk, K)                                          \
                while ((unsigned)((uk) >> 32) != exp_tag) {                    \
                    uk = __hip_atomic_load(base + (K) * 256,                   \
                                           __ATOMIC_RELAXED,                   \
                                           __HIP_MEMORY_SCOPE_SYSTEM);         \
                }                                                              \
                s_h[tid + (K) * 256] = __uint_as_float((unsigned)(uk));
            FINISH_ROW(u0, 0)   FINISH_ROW(u1, 1)   FINISH_ROW(u2, 2)
            FINISH_ROW(u3, 3)   FINISH_ROW(u4, 4)   FINISH_ROW(u5, 5)
            FINISH_ROW(u6, 6)   FINISH_ROW(u7, 7)   FINISH_ROW(u8, 8)
            FINISH_ROW(u9, 9)   FINISH_ROW(u10, 10) FINISH_ROW(u11, 11)
            FINISH_ROW(u12, 12) FINISH_ROW(u13, 13) FINISH_ROW(u14, 14)
            FINISH_ROW(u15, 15)
            #undef FINISH_ROW
            __syncthreads();
        }

        // sparse row-dot: identical order to R4 (16-lane groups, stride 16)
        float acc = 0.0f;
        if (t > 0) {
            for (int e = start + sub; e < start + cnt; e += 16) {
                uint2 p = s_pool[e];
                acc += __uint_as_float(p.x) * s_h[p.y];
            }
        }
        acc += __shfl_xor(acc, 8, 16);
        acc += __shfl_xor(acc, 4, 16);
        acc += __shfl_xor(acc, 2, 16);
        acc += __shfl_xor(acc, 1, 16);

        if (sub == 0) {
            const float* xt = x + (size_t)t * I_DIM;
            float a = acc;
            #pragma unroll
            for (int c = 0; c < I_DIM; ++c) a += s_win[row16][c] * xt[c];
            float h = tanhf(a);
            unsigned long long pk =
                ((unsigned long long)(tag_base + (unsigned)(t + 1)) << 32) |
                (unsigned long long)__float_as_uint(h);
            // single 8B packet: data + tag land atomically at coherence point
            __hip_atomic_store(&g_pack[(size_t)t * R_DIM + row0 + row16], pk,
                               __ATOMIC_RELAXED, __HIP_MEMORY_SCOPE_SYSTEM);
        }
        // no tail barrier: next iteration's leading __syncthreads protects s_h
    }
}

// y_t = Wout h_t + b, one wave per timestep; accumulation order as R4.
__global__ void esn_out_kernel(const float* __restrict__ Wout_w,
                               const float* __restrict__ Wout_b,
                               float* __restrict__ out) {
    const int t = blockIdx.x;
    const int lane = threadIdx.x;  // 64 threads
    const unsigned long long* hp = g_pack + (size_t)t * R_DIM;
    float acc[O_DIM];
    #pragma unroll
    for (int o = 0; o < O_DIM; ++o) acc[o] = 0.0f;
    for (int i = lane; i < R_DIM; i += 256) {   // 16 iters, 4 indep loads each
        unsigned long long u0 = __hip_atomic_load(hp + i,       __ATOMIC_RELAXED, __HIP_MEMORY_SCOPE_SYSTEM);
        unsigned long long u1 = __hip_atomic_load(hp + i + 64,  __ATOMIC_RELAXED, __HIP_MEMORY_SCOPE_SYSTEM);
        unsigned long long u2 = __hip_atomic_load(hp + i + 128, __ATOMIC_RELAXED, __HIP_MEMORY_SCOPE_SYSTEM);
        unsigned long long u3 = __hip_atomic_load(hp + i + 192, __ATOMIC_RELAXED, __HIP_MEMORY_SCOPE_SYSTEM);
        float h0 = __uint_as_float((unsigned)u0);
        float h1 = __uint_as_float((unsigned)u1);
        float h2 = __uint_as_float((unsigned)u2);
        float h3 = __uint_as_float((unsigned)u3);
        #pragma unroll
        for (int o = 0; o < O_DIM; ++o) acc[o] += h0 * Wout_w[(size_t)o * R_DIM + i];
        #pragma unroll
        for (int o = 0; o < O_DIM; ++o) acc[o] += h1 * Wout_w[(size_t)o * R_DIM + i + 64];
        #pragma unroll
        for (int o = 0; o < O_DIM; ++o) acc[o] += h2 * Wout_w[(size_t)o * R_DIM + i + 128];
        #pragma unroll
        for (int o = 0; o < O_DIM; ++o) acc[o] += h3 * Wout_w[(size_t)o * R_DIM + i + 192];
    }
    #pragma unroll
    for (int o = 0; o < O_DIM; ++o) {
        float a = acc[o];
        a += __shfl_xor(a, 32);
        a += __shfl_xor(a, 16);
        a += __shfl_xor(a, 8);
        a += __shfl_xor(a, 4);
        a += __shfl_xor(a, 2);
        a += __shfl_xor(a, 1);
        if (lane == 0) out[(size_t)t * O_DIM + o] = a + Wout_b[o];
    }
}

extern "C" void kernel_launch(void* const* d_in, const int* in_sizes, int n_in,
                              void* d_out, int out_size, void* d_ws, size_t ws_size,
                              hipStream_t stream) {
    const float* x    = (const float*)d_in[0];   // [1,2048,8]
    const float* Win  = (const float*)d_in[1];   // [4096,8]
    const float* W    = (const float*)d_in[2];   // [4096,4096]
    const float* Ww   = (const float*)d_in[3];   // [8,4096]
    const float* Wb   = (const float*)d_in[4];   // [8]
    float* out = (float*)d_out;                  // [1,2048,8]

    hipLaunchKernelGGL(esn_init_kernel, dim3(1), dim3(64), 0, stream);

    void* args[] = { (void*)&x, (void*)&Win, (void*)&W };
    hipLaunchCooperativeKernel((void*)esn_recur_kernel, dim3(NWG), dim3(BLOCK),
                               args, 0, stream);

    hipLaunchKernelGGL(esn_out_kernel, dim3(T_STEPS), dim3(64), 0, stream,
                       Ww, Wb, out);
}

// Round 6
// 10830.848 us; speedup vs baseline: 7.1228x; 1.1976x over previous
//
#include <hip/hip_runtime.h>
#include <math.h>

// ESN reservoir: B=1, T=2048, I=8, R=4096, O=8.
// h_t = tanh(Win x_t + W h_{t-1}); y_t = Wout h_t + b.
//
// R6 = R5 (flagless tag-in-data packets, 8B = tag<<32|float_bits, relaxed
// SYSTEM-scope write-through stores, L2-bypass reads) with the serial
// per-row retry chain replaced by a BATCHED retry: each round re-issues
// all 16 pipelined global_load_dwordx2 sc0 sc1 in one asm block (1 L3 RT
// per round), loops until every tag in the workgroup is fresh. R5 lost
// ~5 us/step to up-to-16 serialized scalar retries.
// Compute & reduction order bit-identical to R4/R5 (absmax 0.0078125).

#define T_STEPS 2048
#define R_DIM   4096
#define I_DIM   8
#define O_DIM   8
#define NWG     256
#define ROWS_PER_WG (R_DIM / NWG)   // 16
#define POOL_CAP 8192               // mean nnz/WG = 6554, ~21 sigma headroom
#define BLOCK    256
#define TAG_MUL  4096

__device__ unsigned long long g_pack[(size_t)T_STEPS * R_DIM];  // 64 MB
__device__ unsigned int      g_epoch;

__global__ void esn_init_kernel() {
    if (threadIdx.x == 0) {
        unsigned e = __hip_atomic_load(&g_epoch, __ATOMIC_RELAXED,
                                       __HIP_MEMORY_SCOPE_SYSTEM) + 1u;
        __hip_atomic_store(&g_epoch, e, __ATOMIC_RELAXED,
                           __HIP_MEMORY_SCOPE_SYSTEM);
    }
}

__launch_bounds__(BLOCK, 1)
__global__ void esn_recur_kernel(const float* __restrict__ x,
                                 const float* __restrict__ Win,
                                 const float* __restrict__ W) {
    __shared__ uint2 s_pool[POOL_CAP];                // 64 KB (val bits, idx)
    __shared__ float s_h[R_DIM];                      // 16 KB
    __shared__ int   s_start[ROWS_PER_WG + 1];
    __shared__ int   s_cnt[ROWS_PER_WG];
    __shared__ float s_win[ROWS_PER_WG][I_DIM];

    const int wg   = blockIdx.x;
    const int tid  = threadIdx.x;
    const int lane = tid & 63;
    const int wave = tid >> 6;
    const int row0 = wg * ROWS_PER_WG;

    const unsigned tag_base =
        __hip_atomic_load(&g_epoch, __ATOMIC_RELAXED,
                          __HIP_MEMORY_SCOPE_SYSTEM) * TAG_MUL;

    // ---------- one-time setup: compact 16 rows of W into LDS (order as R4) ----------
    for (int rr = wave; rr < ROWS_PER_WG; rr += 4) {
        const float* wrow = W + (size_t)(row0 + rr) * R_DIM;
        int cnt = 0;
        for (int base = 0; base < R_DIM; base += 64) {
            float v = wrow[base + lane];
            cnt += __popcll(__ballot(v != 0.0f));
        }
        if (lane == 0) s_cnt[rr] = cnt;
    }
    __syncthreads();
    if (tid == 0) {
        int acc = 0;
        for (int rr = 0; rr < ROWS_PER_WG; ++rr) {
            s_start[rr] = (acc < POOL_CAP) ? acc : POOL_CAP;
            acc += s_cnt[rr];
        }
        s_start[ROWS_PER_WG] = (acc < POOL_CAP) ? acc : POOL_CAP;
    }
    __syncthreads();
    for (int rr = wave; rr < ROWS_PER_WG; rr += 4) {
        const float* wrow = W + (size_t)(row0 + rr) * R_DIM;
        int off = s_start[rr];
        for (int base = 0; base < R_DIM; base += 64) {
            float v = wrow[base + lane];
            unsigned long long m = __ballot(v != 0.0f);
            int pre = __popcll(m & ((1ull << lane) - 1ull));
            if (v != 0.0f) {
                int pos = off + pre;
                if (pos < POOL_CAP) {
                    s_pool[pos].x = __float_as_uint(v);
                    s_pool[pos].y = base + lane;
                }
            }
            off += __popcll(m);
        }
    }
    if (tid < ROWS_PER_WG * I_DIM) {
        int rr = tid / I_DIM, c = tid % I_DIM;
        s_win[rr][c] = Win[(size_t)(row0 + rr) * I_DIM + c];
    }
    __syncthreads();

    const int row16 = tid >> 4;          // 0..15: which of my 16 rows
    const int sub   = tid & 15;          // 16 threads per row (as R4)
    const int start = s_start[row16];
    const int cnt   = s_start[row16 + 1] - start;

    // ---------- time loop ----------
    for (int t = 0; t < T_STEPS; ++t) {
        if (t > 0) {
            const unsigned exp_tag = tag_base + (unsigned)t;  // packets for t-1 carry tag_base+t
            __syncthreads();   // previous step's s_h readers done
            const unsigned long long* base =
                g_pack + (size_t)(t - 1) * R_DIM + tid;
            unsigned long long u0,u1,u2,u3,u4,u5,u6,u7,u8,u9,u10,u11,u12,u13,u14,u15;
            const unsigned long long* a0 = base;
            const unsigned long long* a1 = base + 512;
            const unsigned long long* a2 = base + 1024;
            const unsigned long long* a3 = base + 1536;
            const unsigned long long* a4 = base + 2048;
            const unsigned long long* a5 = base + 2560;
            const unsigned long long* a6 = base + 3072;
            const unsigned long long* a7 = base + 3584;
            // batched wait: each round = 16 loads in flight, 1 L3 round trip.
            // tag match => value final, so unconditional overwrite is safe.
            bool ok;
            do {
                asm volatile(
                    "global_load_dwordx2 %0,  %16, off sc0 sc1\n\t"
                    "global_load_dwordx2 %1,  %16, off offset:2048 sc0 sc1\n\t"
                    "global_load_dwordx2 %2,  %17, off sc0 sc1\n\t"
                    "global_load_dwordx2 %3,  %17, off offset:2048 sc0 sc1\n\t"
                    "global_load_dwordx2 %4,  %18, off sc0 sc1\n\t"
                    "global_load_dwordx2 %5,  %18, off offset:2048 sc0 sc1\n\t"
                    "global_load_dwordx2 %6,  %19, off sc0 sc1\n\t"
                    "global_load_dwordx2 %7,  %19, off offset:2048 sc0 sc1\n\t"
                    "global_load_dwordx2 %8,  %20, off sc0 sc1\n\t"
                    "global_load_dwordx2 %9,  %20, off offset:2048 sc0 sc1\n\t"
                    "global_load_dwordx2 %10, %21, off sc0 sc1\n\t"
                    "global_load_dwordx2 %11, %21, off offset:2048 sc0 sc1\n\t"
                    "global_load_dwordx2 %12, %22, off sc0 sc1\n\t"
                    "global_load_dwordx2 %13, %22, off offset:2048 sc0 sc1\n\t"
                    "global_load_dwordx2 %14, %23, off sc0 sc1\n\t"
                    "global_load_dwordx2 %15, %23, off offset:2048 sc0 sc1\n\t"
                    "s_waitcnt vmcnt(0)"
                    : "=v"(u0), "=v"(u1), "=v"(u2), "=v"(u3),
                      "=v"(u4), "=v"(u5), "=v"(u6), "=v"(u7),
                      "=v"(u8), "=v"(u9), "=v"(u10), "=v"(u11),
                      "=v"(u12), "=v"(u13), "=v"(u14), "=v"(u15)
                    : "v"(a0), "v"(a1), "v"(a2), "v"(a3),
                      "v"(a4), "v"(a5), "v"(a6), "v"(a7)
                    : "memory");
                ok = ((unsigned)(u0  >> 32) == exp_tag) &
                     ((unsigned)(u1  >> 32) == exp_tag) &
                     ((unsigned)(u2  >> 32) == exp_tag) &
                     ((unsigned)(u3  >> 32) == exp_tag) &
                     ((unsigned)(u4  >> 32) == exp_tag) &
                     ((unsigned)(u5  >> 32) == exp_tag) &
                     ((unsigned)(u6  >> 32) == exp_tag) &
                     ((unsigned)(u7  >> 32) == exp_tag) &
                     ((unsigned)(u8  >> 32) == exp_tag) &
                     ((unsigned)(u9  >> 32) == exp_tag) &
                     ((unsigned)(u10 >> 32) == exp_tag) &
                     ((unsigned)(u11 >> 32) == exp_tag) &
                     ((unsigned)(u12 >> 32) == exp_tag) &
                     ((unsigned)(u13 >> 32) == exp_tag) &
                     ((unsigned)(u14 >> 32) == exp_tag) &
                     ((unsigned)(u15 >> 32) == exp_tag);
            } while (!__all(ok));
            s_h[tid]        = __uint_as_float((unsigned)u0);
            s_h[tid + 256]  = __uint_as_float((unsigned)u1);
            s_h[tid + 512]  = __uint_as_float((unsigned)u2);
            s_h[tid + 768]  = __uint_as_float((unsigned)u3);
            s_h[tid + 1024] = __uint_as_float((unsigned)u4);
            s_h[tid + 1280] = __uint_as_float((unsigned)u5);
            s_h[tid + 1536] = __uint_as_float((unsigned)u6);
            s_h[tid + 1792] = __uint_as_float((unsigned)u7);
            s_h[tid + 2048] = __uint_as_float((unsigned)u8);
            s_h[tid + 2304] = __uint_as_float((unsigned)u9);
            s_h[tid + 2560] = __uint_as_float((unsigned)u10);
            s_h[tid + 2816] = __uint_as_float((unsigned)u11);
            s_h[tid + 3072] = __uint_as_float((unsigned)u12);
            s_h[tid + 3328] = __uint_as_float((unsigned)u13);
            s_h[tid + 3584] = __uint_as_float((unsigned)u14);
            s_h[tid + 3840] = __uint_as_float((unsigned)u15);
            __syncthreads();
        }

        // sparse row-dot: identical order to R4/R5 (16-lane groups, stride 16)
        float acc = 0.0f;
        if (t > 0) {
            for (int e = start + sub; e < start + cnt; e += 16) {
                uint2 p = s_pool[e];
                acc += __uint_as_float(p.x) * s_h[p.y];
            }
        }
        acc += __shfl_xor(acc, 8, 16);
        acc += __shfl_xor(acc, 4, 16);
        acc += __shfl_xor(acc, 2, 16);
        acc += __shfl_xor(acc, 1, 16);

        if (sub == 0) {
            const float* xt = x + (size_t)t * I_DIM;
            float a = acc;
            #pragma unroll
            for (int c = 0; c < I_DIM; ++c) a += s_win[row16][c] * xt[c];
            float h = tanhf(a);
            unsigned long long pk =
                ((unsigned long long)(tag_base + (unsigned)(t + 1)) << 32) |
                (unsigned long long)__float_as_uint(h);
            __hip_atomic_store(&g_pack[(size_t)t * R_DIM + row0 + row16], pk,
                               __ATOMIC_RELAXED, __HIP_MEMORY_SCOPE_SYSTEM);
        }
        // no tail barrier: next iteration's leading __syncthreads protects s_h
    }
}

// y_t = Wout h_t + b, one wave per timestep; accumulation order as R4/R5.
__global__ void esn_out_kernel(const float* __restrict__ Wout_w,
                               const float* __restrict__ Wout_b,
                               float* __restrict__ out) {
    const int t = blockIdx.x;
    const int lane = threadIdx.x;  // 64 threads
    const unsigned long long* hp = g_pack + (size_t)t * R_DIM;
    float acc[O_DIM];
    #pragma unroll
    for (int o = 0; o < O_DIM; ++o) acc[o] = 0.0f;
    for (int i = lane; i < R_DIM; i += 256) {   // 16 iters, 4 indep loads each
        unsigned long long u0 = __hip_atomic_load(hp + i,       __ATOMIC_RELAXED, __HIP_MEMORY_SCOPE_SYSTEM);
        unsigned long long u1 = __hip_atomic_load(hp + i + 64,  __ATOMIC_RELAXED, __HIP_MEMORY_SCOPE_SYSTEM);
        unsigned long long u2 = __hip_atomic_load(hp + i + 128, __ATOMIC_RELAXED, __HIP_MEMORY_SCOPE_SYSTEM);
        unsigned long long u3 = __hip_atomic_load(hp + i + 192, __ATOMIC_RELAXED, __HIP_MEMORY_SCOPE_SYSTEM);
        float h0 = __uint_as_float((unsigned)u0);
        float h1 = __uint_as_float((unsigned)u1);
        float h2 = __uint_as_float((unsigned)u2);
        float h3 = __uint_as_float((unsigned)u3);
        #pragma unroll
        for (int o = 0; o < O_DIM; ++o) acc[o] += h0 * Wout_w[(size_t)o * R_DIM + i];
        #pragma unroll
        for (int o = 0; o < O_DIM; ++o) acc[o] += h1 * Wout_w[(size_t)o * R_DIM + i + 64];
        #pragma unroll
        for (int o = 0; o < O_DIM; ++o) acc[o] += h2 * Wout_w[(size_t)o * R_DIM + i + 128];
        #pragma unroll
        for (int o = 0; o < O_DIM; ++o) acc[o] += h3 * Wout_w[(size_t)o * R_DIM + i + 192];
    }
    #pragma unroll
    for (int o = 0; o < O_DIM; ++o) {
        float a = acc[o];
        a += __shfl_xor(a, 32);
        a += __shfl_xor(a, 16);
        a += __shfl_xor(a, 8);
        a += __shfl_xor(a, 4);
        a += __shfl_xor(a, 2);
        a += __shfl_xor(a, 1);
        if (lane == 0) out[(size_t)t * O_DIM + o] = a + Wout_b[o];
    }
}

extern "C" void kernel_launch(void* const* d_in, const int* in_sizes, int n_in,
                              void* d_out, int out_size, void* d_ws, size_t ws_size,
                              hipStream_t stream) {
    const float* x    = (const float*)d_in[0];   // [1,2048,8]
    const float* Win  = (const float*)d_in[1];   // [4096,8]
    const float* W    = (const float*)d_in[2];   // [4096,4096]
    const float* Ww   = (const float*)d_in[3];   // [8,4096]
    const float* Wb   = (const float*)d_in[4];   // [8]
    float* out = (float*)d_out;                  // [1,2048,8]

    hipLaunchKernelGGL(esn_init_kernel, dim3(1), dim3(64), 0, stream);

    void* args[] = { (void*)&x, (void*)&Win, (void*)&W };
    hipLaunchCooperativeKernel((void*)esn_recur_kernel, dim3(NWG), dim3(BLOCK),
                               args, 0, stream);

    hipLaunchKernelGGL(esn_out_kernel, dim3(T_STEPS), dim3(64), 0, stream,
                       Ww, Wb, out);
}